// Round 1
// baseline (549.273 us; speedup 1.0000x reference)
//
#include <hip/hip_runtime.h>
#include <hip/hip_bf16.h>
#include <math.h>

#define HD   512      // H
#define D2   1024     // 2H
#define SEQ  4096
#define BAT  16
#define BM   64
#define BK   32

typedef _Float16 half8 __attribute__((ext_vector_type(8)));
typedef float    f32x4 __attribute__((ext_vector_type(4)));

typedef __attribute__((address_space(3))) void lds_void_t;
typedef __attribute__((address_space(1))) void glb_void_t;

// ---------- kernel 0: W bottom-half -> f16, transposed to [n][k] ----------
__global__ void wconv_kernel(const float* __restrict__ W, _Float16* __restrict__ Wt) {
  __shared__ float tile[32][33];
  const int kb = blockIdx.x * 32;
  const int nb = blockIdx.y * 32;
  const int tx = threadIdx.x & 31;
  const int ty = threadIdx.x >> 5;
  #pragma unroll
  for (int i = 0; i < 4; ++i) {
    int kl = ty + i * 8;
    tile[kl][tx] = W[(size_t)(D2 + kb + kl) * HD + nb + tx];  // coalesced in n
  }
  __syncthreads();
  #pragma unroll
  for (int i = 0; i < 4; ++i) {
    int nl = ty + i * 8;
    Wt[(size_t)(nb + nl) * D2 + kb + tx] = (_Float16)tile[tx][nl];  // coalesced in k
  }
}

// ---------- kernel 1: h_proj[b,h] += hidden[b,:] . W_top[:,h] (atomic) ----------
__global__ void hproj_kernel(const float* __restrict__ hidden,
                             const float* __restrict__ W,
                             float* __restrict__ hproj) {
  const int b  = blockIdx.x >> 3;
  const int kc = blockIdx.x & 7;    // 8 K-chunks of 128
  const int h  = threadIdx.x;       // 256 threads, 2 h each
  float a0 = 0.f, a1 = 0.f;
  #pragma unroll 4
  for (int i = 0; i < 128; ++i) {
    const int d = kc * 128 + i;
    const float hd = hidden[b * D2 + d];          // wave-uniform (scalar load)
    a0 += hd * W[(size_t)d * HD + h];             // coalesced
    a1 += hd * W[(size_t)d * HD + h + 256];
  }
  atomicAdd(&hproj[b * HD + h], a0);
  atomicAdd(&hproj[b * HD + h + 256], a1);
}

// ---------- kernel 2: scores[b,s] = w_v . tanh(enc.Wbot + h_proj + b_attn) ----------
// Block: 64 rows x all 512 n. 4 waves: wave = (strip: rows strip*32..+31) x (nhalf: n 256-half).
// Per K-step/wave: 2 A-frag reads + 16 B-frag reads -> 32 MFMAs (B-frag reused for 2 strips).
__global__ __launch_bounds__(256, 2) void scores_kernel(
    const float* __restrict__ enc, const _Float16* __restrict__ Wt,
    const float* __restrict__ hproj, const float* __restrict__ b_attn,
    const float* __restrict__ w_v, float* __restrict__ scores)
{
  __shared__ __align__(16) _Float16 As[BM][BK + 8];   // +8 pad: 80B rows, 2-way max
  __shared__ __align__(16) _Float16 Bs[HD * BK];      // [n][4 chunks of 8 f16], XOR-swizzled

  const int b    = blockIdx.y;
  const int s0   = blockIdx.x * BM;
  const int tid  = threadIdx.x;
  const int lane = tid & 63;
  const int wave = tid >> 6;
  const int strip = wave >> 1;
  const int nhalf = wave & 1;
  const int col  = lane & 15;
  const int quad = lane >> 4;

  const float* encB = enc + ((size_t)b * SEQ + s0) * D2;

  f32x4 acc0[16], acc1[16];
  const f32x4 z = {0.f, 0.f, 0.f, 0.f};
  #pragma unroll
  for (int i = 0; i < 16; ++i) { acc0[i] = z; acc1[i] = z; }

  const int arow = tid >> 2;   // 0..63
  const int akq  = tid & 3;    // k sub-chunk (8 f32)

  for (int kt = 0; kt < D2 / BK; ++kt) {
    __syncthreads();           // protect LDS from previous iteration's readers
    // ---- stage A tile: 64 rows x 32 k, f32 -> f16 ----
    {
      const float* src = encB + (size_t)arow * D2 + kt * BK + akq * 8;
      f32x4 v0 = *(const f32x4*)(src);
      f32x4 v1 = *(const f32x4*)(src + 4);
      half8 hv;
      hv[0] = (_Float16)v0[0]; hv[1] = (_Float16)v0[1];
      hv[2] = (_Float16)v0[2]; hv[3] = (_Float16)v0[3];
      hv[4] = (_Float16)v1[0]; hv[5] = (_Float16)v1[1];
      hv[6] = (_Float16)v1[2]; hv[7] = (_Float16)v1[3];
      *(half8*)&As[arow][akq * 8] = hv;
    }
    // ---- stage B tile: 512 n x 32 k via global_load_lds (16B/lane, swizzled) ----
    #pragma unroll
    for (int i = 0; i < 8; ++i) {
      const int c   = i * 256 + tid;   // LDS chunk slot; lane-contiguous within wave
      const int n   = c >> 2;
      const int khs = c & 3;
      const int kg  = khs ^ (n & 3);   // XOR swizzle for bank balance
      __builtin_amdgcn_global_load_lds(
          (glb_void_t*)((const char*)Wt + (size_t)n * (D2 * 2) + (size_t)kt * 64 + kg * 16),
          (lds_void_t*)((char*)Bs + c * 16), 16, 0, 0);
    }
    __syncthreads();
    // ---- compute ----
    half8 a0 = *(const half8*)&As[strip * 32 + col][quad * 8];
    half8 a1 = *(const half8*)&As[strip * 32 + 16 + col][quad * 8];
    #pragma unroll
    for (int nt = 0; nt < 16; ++nt) {
      const int n = nhalf * 256 + nt * 16 + col;
      half8 bf = *(const half8*)((const char*)Bs + n * 64 + ((quad ^ (n & 3)) * 16));
      acc0[nt] = __builtin_amdgcn_mfma_f32_16x16x32_f16(a0, bf, acc0[nt], 0, 0, 0);
      acc1[nt] = __builtin_amdgcn_mfma_f32_16x16x32_f16(a1, bf, acc1[nt], 0, 0, 0);
    }
  }

  // ---- epilogue: tanh + dot(w_v), reduce over n ----
  // D layout: col = lane&15 (n), row = quad*4 + reg  [m89-verified]
  float p0[4] = {0.f, 0.f, 0.f, 0.f}, p1[4] = {0.f, 0.f, 0.f, 0.f};
  const float* hp = hproj + b * HD;
  #pragma unroll
  for (int nt = 0; nt < 16; ++nt) {
    const int n = nhalf * 256 + nt * 16 + col;
    const float hb = hp[n] + b_attn[n];
    const float wv = w_v[n];
    #pragma unroll
    for (int r = 0; r < 4; ++r) {
      p0[r] += wv * tanhf(acc0[nt][r] + hb);
      p1[r] += wv * tanhf(acc1[nt][r] + hb);
    }
  }
  #pragma unroll
  for (int off = 8; off >= 1; off >>= 1) {
    #pragma unroll
    for (int r = 0; r < 4; ++r) {
      p0[r] += __shfl_xor(p0[r], off, 64);
      p1[r] += __shfl_xor(p1[r], off, 64);
    }
  }
  if (col == 0) {
    const int m0 = s0 + strip * 32 + quad * 4;
    #pragma unroll
    for (int r = 0; r < 4; ++r) {   // two n-halves (waves) sum via atomics
      atomicAdd(&scores[b * SEQ + m0 + r], p0[r]);
      atomicAdd(&scores[b * SEQ + m0 + 16 + r], p1[r]);
    }
  }
}

// ---------- kernel 3: softmax over S, in place ----------
__global__ void softmax_kernel(float* __restrict__ scores) {
  const int b = blockIdx.x;
  float* sc = scores + b * SEQ;
  __shared__ float red[16];
  const int tid = threadIdx.x;   // 256
  float loc[16];
  float mx = -1e30f;
  #pragma unroll
  for (int i = 0; i < 16; ++i) { loc[i] = sc[i * 256 + tid]; mx = fmaxf(mx, loc[i]); }
  #pragma unroll
  for (int off = 32; off >= 1; off >>= 1) mx = fmaxf(mx, __shfl_xor(mx, off, 64));
  if ((tid & 63) == 0) red[tid >> 6] = mx;
  __syncthreads();
  mx = fmaxf(fmaxf(red[0], red[1]), fmaxf(red[2], red[3]));
  float sum = 0.f;
  #pragma unroll
  for (int i = 0; i < 16; ++i) { loc[i] = __expf(loc[i] - mx); sum += loc[i]; }
  #pragma unroll
  for (int off = 32; off >= 1; off >>= 1) sum += __shfl_xor(sum, off, 64);
  if ((tid & 63) == 0) red[8 + (tid >> 6)] = sum;
  __syncthreads();
  sum = red[8] + red[9] + red[10] + red[11];
  const float inv = 1.0f / sum;
  #pragma unroll
  for (int i = 0; i < 16; ++i) sc[i * 256 + tid] = loc[i] * inv;
}

// ---------- kernel 4: context[b,d] = sum_s attn[b,s] * enc[b,s,d] ----------
__global__ void context_kernel(const float* __restrict__ attn,
                               const float* __restrict__ enc,
                               float* __restrict__ out) {
  const int b  = blockIdx.y;
  const int s0 = blockIdx.x * 128;
  const int tid = threadIdx.x;   // 256 threads * float4 = 1024 d
  f32x4 acc = {0.f, 0.f, 0.f, 0.f};
  const float* encB = enc + ((size_t)b * SEQ + s0) * D2;
  const float* at = attn + b * SEQ + s0;
  for (int i = 0; i < 128; ++i) {
    const float a = at[i];                               // wave-uniform
    f32x4 v = *(const f32x4*)(encB + (size_t)i * D2 + tid * 4);  // coalesced 16B/lane
    acc += v * a;
  }
  float* o = out + b * D2 + tid * 4;
  atomicAdd(o + 0, acc[0]);
  atomicAdd(o + 1, acc[1]);
  atomicAdd(o + 2, acc[2]);
  atomicAdd(o + 3, acc[3]);
}

extern "C" void kernel_launch(void* const* d_in, const int* in_sizes, int n_in,
                              void* d_out, int out_size, void* d_ws, size_t ws_size,
                              hipStream_t stream) {
  (void)in_sizes; (void)n_in; (void)ws_size;
  const float* hidden = (const float*)d_in[0];   // [16,1024]
  const float* enc    = (const float*)d_in[1];   // [16,4096,1024]
  const float* W      = (const float*)d_in[2];   // [2048,512]
  const float* b_attn = (const float*)d_in[3];   // [512]
  const float* w_v    = (const float*)d_in[4];   // [512]
  float* out = (float*)d_out;                    // [16,1024]

  char* ws = (char*)d_ws;
  _Float16* Wt  = (_Float16*)ws;                     // 1 MB:  Wbot^T f16 [512][1024]
  float* hproj  = (float*)(ws + (1 << 20));          // 32 KB: [16][512]
  float* scores = (float*)(ws + (1 << 20) + 32768);  // 256 KB:[16][4096], reused as attn

  hipMemsetAsync(d_out, 0, (size_t)out_size * sizeof(float), stream);
  hipMemsetAsync(hproj, 0, BAT * HD * sizeof(float), stream);
  hipMemsetAsync(scores, 0, (size_t)BAT * SEQ * sizeof(float), stream);

  wconv_kernel  <<<dim3(32, 16),        256, 0, stream>>>(W, Wt);
  hproj_kernel  <<<dim3(128),           256, 0, stream>>>(hidden, W, hproj);
  scores_kernel <<<dim3(SEQ / BM, BAT), 256, 0, stream>>>(enc, Wt, hproj, b_attn, w_v, scores);
  softmax_kernel<<<dim3(BAT),           256, 0, stream>>>(scores);
  context_kernel<<<dim3(SEQ / 128, BAT),256, 0, stream>>>(scores, enc, out);
}

// Round 2
// 491.841 us; speedup vs baseline: 1.1168x; 1.1168x over previous
//
#include <hip/hip_runtime.h>
#include <hip/hip_bf16.h>
#include <math.h>

#define HD   512
#define D2   1024
#define SEQ  4096
#define BAT  16
#define BM   64      // s-rows per block
#define BN   256     // n-cols per block (n-half)
#define BK   32

typedef _Float16 half8 __attribute__((ext_vector_type(8)));
typedef float    f32x4 __attribute__((ext_vector_type(4)));
typedef __attribute__((address_space(3))) void lds_void_t;
typedef __attribute__((address_space(1))) void glb_void_t;

// ---------- kernel 0: W bottom-half -> f16, shuffled tile-major ----------
// WtS chunk layout: [kt 0..31][nh 0..1][c 0..1023] of 16B chunks,
// c = nbl*64 + kc*16 + nlo ; n = nh*256 + nbl*16 + nlo ; k = kt*32 + kc*8 + j.
// This makes scores' B staging a LINEAR global->LDS copy and B-frag reads
// phase-contiguous (0 bank conflicts).
__global__ void wconv_kernel(const float* __restrict__ W, _Float16* __restrict__ WtS) {
  __shared__ float tile[32][17];
  const int kt  = blockIdx.x;        // 0..31
  const int nbg = blockIdx.y;        // 0..31
  const int nh  = nbg >> 4, nbl = nbg & 15;
  const int t   = threadIdx.x;       // 256
  {
    const int n16 = t & 15, kk = t >> 4;   // kk 0..15
    #pragma unroll
    for (int i = 0; i < 2; ++i) {
      const int k = kk + i * 16;
      tile[k][n16] = W[(size_t)(D2 + kt * 32 + k) * HD + nh * 256 + nbl * 16 + n16];
    }
  }
  __syncthreads();
  if (t < 64) {
    const int kc = t >> 4, nlo = t & 15;
    half8 h;
    #pragma unroll
    for (int j = 0; j < 8; ++j) h[j] = (_Float16)tile[kc * 8 + j][nlo];
    *(half8*)(WtS + ((size_t)(kt * 2 + nh) * 1024 + nbl * 64 + kc * 16 + nlo) * 8) = h;
  }
}

// ---------- kernel 1: h_proj[b,h] = hidden[b,:] . W_top[:,h] (atomic) ----------
__global__ void hproj_kernel(const float* __restrict__ hidden,
                             const float* __restrict__ W,
                             float* __restrict__ hproj) {
  const int b  = blockIdx.x >> 3;
  const int kc = blockIdx.x & 7;
  const int h  = threadIdx.x;
  float a0 = 0.f, a1 = 0.f;
  #pragma unroll 4
  for (int i = 0; i < 128; ++i) {
    const int d = kc * 128 + i;
    const float hd = hidden[b * D2 + d];
    a0 += hd * W[(size_t)d * HD + h];
    a1 += hd * W[(size_t)d * HD + h + 256];
  }
  atomicAdd(&hproj[b * HD + h], a0);
  atomicAdd(&hproj[b * HD + h + 256], a1);
}

// ---------- kernel 2: scores = w_v . tanh(enc.Wbot + h_proj + b_attn) ----------
// 256 threads / 4 waves. Block tile M=64 x N=256 (nh half). Wave: M=32 x N=128.
// B: LDS double-buffer, global_load_lds issued BEFORE compute.
// A: 2-deep register prefetch (HBM latency), then ds_write to frag-major LDS.
__global__ __launch_bounds__(256, 4) void scores_kernel(
    const float* __restrict__ enc, const _Float16* __restrict__ WtS,
    const float* __restrict__ hproj, const float* __restrict__ b_attn,
    const float* __restrict__ w_v, float* __restrict__ scores)
{
  __shared__ __align__(16) _Float16 As[2][BM * BK];   // frag-major, 4KB each
  __shared__ __align__(16) _Float16 Bs[2][BN * BK];   // chunk-major, 16KB each

  const int s0  = blockIdx.x * BM;
  const int nh  = blockIdx.y;
  const int b   = blockIdx.z;
  const int tid = threadIdx.x, lane = tid & 63, w = tid >> 6;
  const int col = lane & 15, quad = lane >> 4;
  const int strip = w >> 1, nq2 = w & 1;

  const float* encB = enc + ((size_t)b * SEQ + s0) * D2;
  const _Float16* WtB = WtS + (size_t)nh * 1024 * 8;   // + kt*16384 halves per kt

  // A staging: thread t loads 8 f32 of row (t>>2), k-chunk (t&3)
  const int arow = tid >> 2, akc = tid & 3;
  const float* aSrcBase = encB + (size_t)arow * D2 + akc * 8;
  const int aDstOff = (akc * 64 + (arow ^ (akc << 2))) * 8;       // halves
  // A-frag read offsets (conflict-free with the xor swizzle)
  const int a0off = (quad * 64 + ((strip * 32 + col)      ^ (quad << 2))) * 8;
  const int a1off = (quad * 64 + ((strip * 32 + 16 + col) ^ (quad << 2))) * 8;

  f32x4 acc0[8], acc1[8];
  const f32x4 z = {0.f, 0.f, 0.f, 0.f};
  #pragma unroll
  for (int i = 0; i < 8; ++i) { acc0[i] = z; acc1[i] = z; }

  f32x4 Ra0, Ra1, Rb0, Rb1;

  auto loadA = [&](int kt, f32x4& v0, f32x4& v1) {
    const float* p = aSrcBase + kt * BK;
    v0 = *(const f32x4*)p;
    v1 = *(const f32x4*)(p + 4);
  };
  auto storeA = [&](int buf, const f32x4& v0, const f32x4& v1) {
    half8 h;
    h[0] = (_Float16)v0[0]; h[1] = (_Float16)v0[1];
    h[2] = (_Float16)v0[2]; h[3] = (_Float16)v0[3];
    h[4] = (_Float16)v1[0]; h[5] = (_Float16)v1[1];
    h[6] = (_Float16)v1[2]; h[7] = (_Float16)v1[3];
    *(half8*)&As[buf][aDstOff] = h;
  };
  auto issueB = [&](int kt, int buf) {
    #pragma unroll
    for (int i = 0; i < 4; ++i) {
      const int c = i * 256 + tid;
      __builtin_amdgcn_global_load_lds(
          (glb_void_t*)(WtB + (size_t)kt * 16384 + c * 8),
          (lds_void_t*)((char*)&Bs[buf][0] + c * 16), 16, 0, 0);
    }
  };
  auto compute = [&](int buf) {
    half8 a0 = *(const half8*)&As[buf][a0off];
    half8 a1 = *(const half8*)&As[buf][a1off];
    #pragma unroll
    for (int nt = 0; nt < 8; ++nt) {
      const int nbl_local = nq2 * 8 + nt;
      half8 bf = *(const half8*)&Bs[buf][(nbl_local * 64 + quad * 16 + col) * 8];
      acc0[nt] = __builtin_amdgcn_mfma_f32_16x16x32_f16(a0, bf, acc0[nt], 0, 0, 0);
      acc1[nt] = __builtin_amdgcn_mfma_f32_16x16x32_f16(a1, bf, acc1[nt], 0, 0, 0);
    }
  };

  // prologue: kt=0 into buf0; A(1) into Rb
  loadA(0, Ra0, Ra1);
  storeA(0, Ra0, Ra1);
  issueB(0, 0);
  loadA(1, Rb0, Rb1);
  __syncthreads();

  #pragma unroll 2
  for (int kt = 0; kt < 32; ++kt) {
    const int cur = kt & 1, nxt = cur ^ 1;
    if (kt + 1 < 32) issueB(kt + 1, nxt);              // in flight across compute
    if (kt + 2 < 32) {                                  // 2-deep A reg prefetch
      if (kt & 1) loadA(kt + 2, Rb0, Rb1);
      else        loadA(kt + 2, Ra0, Ra1);
    }
    compute(cur);
    if (kt + 1 < 32) {                                  // A(kt+1): loaded one kt ago
      if (kt & 1) storeA(nxt, Ra0, Ra1);
      else        storeA(nxt, Rb0, Rb1);
    }
    __syncthreads();
  }

  // ---- epilogue: tanh + dot(w_v), reduce over n ----
  float p0[4] = {0.f, 0.f, 0.f, 0.f}, p1[4] = {0.f, 0.f, 0.f, 0.f};
  const float* hp = hproj + b * HD + nh * 256;
  #pragma unroll
  for (int nt = 0; nt < 8; ++nt) {
    const int nl = nq2 * 128 + nt * 16 + col;          // within block's 256
    const float hb = hp[nl] + b_attn[nh * 256 + nl];
    const float wv = w_v[nh * 256 + nl];
    #pragma unroll
    for (int r = 0; r < 4; ++r) {
      {
        float x = fminf(fmaxf(acc0[nt][r] + hb, -15.f), 15.f);
        float ex = __expf(2.f * x);
        p0[r] += wv * __fdividef(ex - 1.f, ex + 1.f);
      }
      {
        float x = fminf(fmaxf(acc1[nt][r] + hb, -15.f), 15.f);
        float ex = __expf(2.f * x);
        p1[r] += wv * __fdividef(ex - 1.f, ex + 1.f);
      }
    }
  }
  #pragma unroll
  for (int off = 8; off >= 1; off >>= 1) {
    #pragma unroll
    for (int r = 0; r < 4; ++r) {
      p0[r] += __shfl_xor(p0[r], off, 64);
      p1[r] += __shfl_xor(p1[r], off, 64);
    }
  }
  if (col == 0) {
    const int m0 = s0 + strip * 32 + quad * 4;
    #pragma unroll
    for (int r = 0; r < 4; ++r) {   // 4-way atomic over (nh, nq2)
      atomicAdd(&scores[b * SEQ + m0 + r], p0[r]);
      atomicAdd(&scores[b * SEQ + m0 + 16 + r], p1[r]);
    }
  }
}

// ---------- kernel 3: softmax over S, in place ----------
__global__ void softmax_kernel(float* __restrict__ scores) {
  const int b = blockIdx.x;
  float* sc = scores + b * SEQ;
  __shared__ float red[16];
  const int tid = threadIdx.x;   // 256
  float loc[16];
  float mx = -1e30f;
  #pragma unroll
  for (int i = 0; i < 16; ++i) { loc[i] = sc[i * 256 + tid]; mx = fmaxf(mx, loc[i]); }
  #pragma unroll
  for (int off = 32; off >= 1; off >>= 1) mx = fmaxf(mx, __shfl_xor(mx, off, 64));
  if ((tid & 63) == 0) red[tid >> 6] = mx;
  __syncthreads();
  mx = fmaxf(fmaxf(red[0], red[1]), fmaxf(red[2], red[3]));
  float sum = 0.f;
  #pragma unroll
  for (int i = 0; i < 16; ++i) { loc[i] = __expf(loc[i] - mx); sum += loc[i]; }
  #pragma unroll
  for (int off = 32; off >= 1; off >>= 1) sum += __shfl_xor(sum, off, 64);
  if ((tid & 63) == 0) red[8 + (tid >> 6)] = sum;
  __syncthreads();
  sum = red[8] + red[9] + red[10] + red[11];
  const float inv = 1.0f / sum;
  #pragma unroll
  for (int i = 0; i < 16; ++i) sc[i * 256 + tid] = loc[i] * inv;
}

// ---------- kernel 4: context[b,d] = sum_s attn[b,s] * enc[b,s,d] ----------
__global__ __launch_bounds__(256) void context_kernel(const float* __restrict__ attn,
                                                      const float* __restrict__ enc,
                                                      float* __restrict__ out) {
  const int b  = blockIdx.y;
  const int s0 = blockIdx.x * 64;
  const int tid = threadIdx.x;   // 256 threads * float4 = 1024 d
  const float* encB = enc + ((size_t)b * SEQ + s0) * D2 + tid * 4;
  const float* at   = attn + b * SEQ + s0;
  f32x4 acc0 = {0.f, 0.f, 0.f, 0.f}, acc1 = {0.f, 0.f, 0.f, 0.f};
  #pragma unroll 8
  for (int i = 0; i < 64; i += 2) {
    acc0 += at[i]     * *(const f32x4*)(encB + (size_t)i * D2);
    acc1 += at[i + 1] * *(const f32x4*)(encB + (size_t)(i + 1) * D2);
  }
  f32x4 acc = acc0 + acc1;
  float* o = out + b * D2 + tid * 4;
  atomicAdd(o + 0, acc[0]);
  atomicAdd(o + 1, acc[1]);
  atomicAdd(o + 2, acc[2]);
  atomicAdd(o + 3, acc[3]);
}

extern "C" void kernel_launch(void* const* d_in, const int* in_sizes, int n_in,
                              void* d_out, int out_size, void* d_ws, size_t ws_size,
                              hipStream_t stream) {
  (void)in_sizes; (void)n_in; (void)ws_size;
  const float* hidden = (const float*)d_in[0];   // [16,1024]
  const float* enc    = (const float*)d_in[1];   // [16,4096,1024]
  const float* W      = (const float*)d_in[2];   // [2048,512]
  const float* b_attn = (const float*)d_in[3];   // [512]
  const float* w_v    = (const float*)d_in[4];   // [512]
  float* out = (float*)d_out;                    // [16,1024]

  char* ws = (char*)d_ws;
  _Float16* WtS = (_Float16*)ws;                     // 1 MB shuffled Wbot f16
  float* hproj  = (float*)(ws + (1 << 20));          // 32 KB
  float* scores = (float*)(ws + (1 << 20) + 32768);  // 256 KB (reused as attn)

  hipMemsetAsync(d_out, 0, (size_t)out_size * sizeof(float), stream);
  hipMemsetAsync(hproj, 0, BAT * HD * sizeof(float), stream);
  hipMemsetAsync(scores, 0, (size_t)BAT * SEQ * sizeof(float), stream);

  wconv_kernel  <<<dim3(32, 32),            256, 0, stream>>>(W, WtS);
  hproj_kernel  <<<dim3(128),               256, 0, stream>>>(hidden, W, hproj);
  scores_kernel <<<dim3(SEQ / BM, 2, BAT),  256, 0, stream>>>(enc, WtS, hproj, b_attn, w_v, scores);
  softmax_kernel<<<dim3(BAT),               256, 0, stream>>>(scores);
  context_kernel<<<dim3(SEQ / 64, BAT),     256, 0, stream>>>(scores, enc, out);
}